// Round 8
// baseline (226.910 us; speedup 1.0000x reference)
//
#include <hip/hip_runtime.h>

// Projector: out[n,p,o] = x@Wd^T + bd + softmax_l((x@W1^T)·(t@W2^T)^T) @ (t@W3^T + b3)
// N=16, HW=3136, L=64, C_IN=256, C_OUT=512, D=256. fp32 in/out.
// R12 = R11 with the epilogue-scratch geometry bug fixed.
//   R11 failed (absmax 8.75): scratch was 16x36/wave (R8's o-split geometry)
//   but the no-split epilogue writes o_local in [0,64) -> row overlap. Fix:
//   dedicated 16x68 f32 per wave (4352 B, 34,816 B total), LDS 78,848 B.
//  (a) main: swapped-operand GEMM3/4 (R10-verified) + full-line LDS-transpose
//      epilogue (R10's direct scatter cost +32MB WRITE / +16MB FETCH from
//      partial-line write-allocate). sc writes are f32x4. Nontemporal stores
//      keep the 103MB out stream from evicting weights from L2. GEMM4 between
//      aw-write and B3 (no aw dep) fills barrier skew.
//  (b) side: Gt scalar loop removed via Mt = (t@W2^T)@W1: verified tq GEMM ->
//      LDS-staged per-n Mt GEMM (16 blocks). prep reblocks W1^T.
// main phases: stage -> B1 -> GEMM2 -> partials -> B2 -> merge/aw -> GEMM4
//   -> B3 -> GEMM3 -> per-ptt epi (f32x4 LDS transpose, nt full-line stores).

typedef unsigned short u16;
using half8 = __attribute__((ext_vector_type(8))) _Float16;
using f32x4 = __attribute__((ext_vector_type(4))) float;

__device__ __forceinline__ u16 f2h(float f) {
  _Float16 h = (_Float16)f;            // RNE
  union { _Float16 h; u16 u; } cv; cv.h = h;
  return cv.u;
}

__device__ __forceinline__ f32x4 mfma16(half8 a, half8 b, f32x4 c) {
  return __builtin_amdgcn_mfma_f32_16x16x32_f16(a, b, c, 0, 0, 0);
}

// ---------------------------------------------------------------------------
// K0: fp32 -> f16 + reblock into fragment-linear layout (KC=8 k-chunks).
// flat = ((row/16)*8 + k/32)*512 + ((k/8)%4)*128 + (row%16)*8 + (k%8)
// b<256 writes W1T (W1T[c][d] = W1[d][c], strided read — tiny, L2-absorbed).
// ---------------------------------------------------------------------------
__global__ __launch_bounds__(256) void prep_kernel(
    const float* __restrict__ W1, const float* __restrict__ W2,
    const float* __restrict__ W3, const float* __restrict__ Wd,
    const float* __restrict__ t,
    u16* __restrict__ W1Tf, u16* __restrict__ W2f, u16* __restrict__ W3f,
    u16* __restrict__ Wdf, u16* __restrict__ tf) {
  int b = blockIdx.x, k = threadIdx.x;
  float v; u16* dst; int row;
  if (b < 256)       { dst = W1Tf; row = b;        v = W1[(size_t)k*256 + b]; }
  else if (b < 512)  { dst = W2f;  row = b - 256;  v = W2[(size_t)row*256 + k]; }
  else if (b < 1024) { dst = W3f;  row = b - 512;  v = W3[(size_t)row*256 + k]; }
  else if (b < 1536) { dst = Wdf;  row = b - 1024; v = Wd[(size_t)row*256 + k]; }
  else               { dst = tf;   row = b - 1536; v = t[(size_t)row*256 + k]; }
  int flat = ((row >> 4)*8 + (k >> 5))*512 + ((k >> 3) & 3)*128 + (row & 15)*8 + (k & 7);
  dst[flat] = f2h(v);
}

// ---------------------------------------------------------------------------
// K1: blocks 0..15: per-n fused tq -> Mt (two-stage, tq staged FL in LDS):
//       tq[n,l,d] = t@W2^T ; Mt[n,l,c] = tq@W1 (B = W1T rows c) -> mtf FL.
//     blocks 16..143: t3[n,o,l] = t@W3^T + b3 -> t3f FL.
// ---------------------------------------------------------------------------
__global__ __launch_bounds__(256) void mt_t3_kernel(
    const u16* __restrict__ tf, const u16* __restrict__ W1Tf,
    const u16* __restrict__ W2f, const u16* __restrict__ W3f,
    const float* __restrict__ b3,
    u16* __restrict__ mtf, u16* __restrict__ t3f) {
  __shared__ u16 tqs[16384];   // 64 x 256 FL f16 (32 KB), used by b<16 only
  const int tid = threadIdx.x, w = tid >> 6, lane = tid & 63;
  const int quad = lane >> 4, l16 = lane & 15;
  const int b = blockIdx.x;

  if (b < 16) {
    const int n = b;
    // ---- stage 1: tq = t @ W2^T (rows l, K=d), write FL into LDS ----
    #pragma unroll
    for (int q = 0; q < 4; ++q) {
      const int g = q*4 + w;             // d-row group (d0 = g*16)
      f32x4 acc[4];
      #pragma unroll
      for (int mt = 0; mt < 4; ++mt) acc[mt] = (f32x4){0.f, 0.f, 0.f, 0.f};
      #pragma unroll
      for (int kc = 0; kc < 8; ++kc) {
        half8 bf = *(const half8*)(W2f + (g*8 + kc)*512 + lane*8);
        #pragma unroll
        for (int mt = 0; mt < 4; ++mt) {
          half8 a = *(const half8*)(tf + ((n*4 + mt)*8 + kc)*512 + lane*8);
          acc[mt] = mfma16(a, bf, acc[mt]);
        }
      }
      // value at (l = mt*16+quad*4+r, d = g*16+l16) -> FL in LDS
      #pragma unroll
      for (int mt = 0; mt < 4; ++mt)
        #pragma unroll
        for (int r = 0; r < 4; ++r)
          tqs[(mt*8 + (g >> 1))*512 + ((g & 1)*2 + (l16 >> 3))*128
              + (quad*4 + r)*8 + (l16 & 7)] = f2h(acc[mt][r]);
    }
    __syncthreads();
    // ---- stage 2: Mt = tq @ W1 (B = W1T rows c, K=d) -> mtf FL ----
    #pragma unroll
    for (int q = 0; q < 4; ++q) {
      const int gc = q*4 + w;            // c-row group (c0 = gc*16)
      f32x4 acc[4];
      #pragma unroll
      for (int mt = 0; mt < 4; ++mt) acc[mt] = (f32x4){0.f, 0.f, 0.f, 0.f};
      #pragma unroll
      for (int kc = 0; kc < 8; ++kc) {
        half8 bf = *(const half8*)(W1Tf + (gc*8 + kc)*512 + lane*8);
        #pragma unroll
        for (int mt = 0; mt < 4; ++mt) {
          half8 a = *(const half8*)(&tqs[(mt*8 + kc)*512 + lane*8]);
          acc[mt] = mfma16(a, bf, acc[mt]);
        }
      }
      // value at (l = mt*16+quad*4+r, c = gc*16+l16); write FL for GEMM2
      #pragma unroll
      for (int mt = 0; mt < 4; ++mt)
        #pragma unroll
        for (int r = 0; r < 4; ++r)
          mtf[((n*4 + mt)*8 + (gc >> 1))*512 + ((gc & 1)*2 + (l16 >> 3))*128
              + (quad*4 + r)*8 + (l16 & 7)] = f2h(acc[mt][r]);
    }
  } else {
    const int b2 = b - 16;
    const int n = b2 >> 3, ob = b2 & 7;
    const int gW3 = ob*4 + w;          // o-row group (o0 = ob*64 + w*16)
    f32x4 acc[4];
    #pragma unroll
    for (int nt = 0; nt < 4; ++nt) acc[nt] = (f32x4){0.f, 0.f, 0.f, 0.f};
    #pragma unroll
    for (int kc = 0; kc < 8; ++kc) {
      half8 a = *(const half8*)(W3f + (gW3*8 + kc)*512 + lane*8);
      #pragma unroll
      for (int nt = 0; nt < 4; ++nt) {
        half8 bf = *(const half8*)(tf + ((n*4 + nt)*8 + kc)*512 + lane*8);
        acc[nt] = mfma16(a, bf, acc[nt]);
      }
    }
    // value at (o = ob*64+w*16+quad*4+r, l = nt*16+l16); write FL for GEMM3
    #pragma unroll
    for (int nt = 0; nt < 4; ++nt)
      #pragma unroll
      for (int r = 0; r < 4; ++r) {
        int o = ob*64 + w*16 + quad*4 + r;
        int flat = ((n*32 + ob*4 + w)*2 + (nt >> 1))*512
                 + ((nt & 1)*2 + (l16 >> 3))*128 + (quad*4 + r)*8 + (l16 & 7);
        t3f[flat] = f2h(acc[nt][r] + b3[o]);
      }
  }
}

// ---------------------------------------------------------------------------
// K2: main fused kernel. grid 784 = 16 n * 49 row-tiles of 64; 512 threads.
// smem carve (78,848 B):
//   [0, 33792):       xs 64 x 264 u16
//   [33792, 43008):   aw 64 x 72 u16
//   [43008, 44032):   parts 64 x 2 x {mx,ps} f32
//   [44032, 78848):   epi scratch, 8 waves x 16 x 68 f32 (4352 B, wave-private)
// 3 barriers. acc[4][4]=64 AGPR, VGPR ~64 (R10-verified shape).
// ---------------------------------------------------------------------------
__global__ __launch_bounds__(512, 4) void main_kernel(
    const float* __restrict__ x, const u16* __restrict__ Wdf,
    const u16* __restrict__ mtf, const u16* __restrict__ t3f,
    const float* __restrict__ bd, float* __restrict__ out) {
  __shared__ __attribute__((aligned(16))) char smem[78848];
  u16* xs = (u16*)smem;                      // 64 x 264
  u16* aw = (u16*)(smem + 33792);            // 64 x 72
  float* parts = (float*)(smem + 43008);     // 64 x 2 x {mx, ps}
  float* scb = (float*)(smem + 44032);       // 8 x (16 x 68) f32

  const int bid = blockIdx.x;
  const int n  = bid / 49;
  const int pt = bid - n*49;
  const int m0 = pt * 64;
  const int tid = threadIdx.x, w = tid >> 6, lane = tid & 63;
  const int quad = lane >> 4, l16 = lane & 15;
  const int rg = w & 3;        // GEMM2 row-group (rows rg*16..rg*16+15)
  const int lp = w >> 2;       // GEMM2 l-pair (l-groups lp*2, lp*2+1)

  // bias as f32x4 per ot-block: bd[w*64 + ot*16 + quad*4 .. +3]
  f32x4 bias4[4];
  #pragma unroll
  for (int ot = 0; ot < 4; ++ot)
    bias4[ot] = *(const f32x4*)&bd[w*64 + ot*16 + quad*4];

  // ---- stage x tile: 64x256 fp32 -> f16 LDS (coalesced float4) ----
  {
    const float4* xg = (const float4*)(x + (size_t)(n*3136 + m0)*256);
    #pragma unroll
    for (int it = 0; it < 8; ++it) {
      int idx = it*512 + tid;
      int r = idx >> 6, c4 = idx & 63;
      float4 v = xg[idx];
      ushort4 u;
      u.x = f2h(v.x); u.y = f2h(v.y); u.z = f2h(v.z); u.w = f2h(v.w);
      *(ushort4*)(&xs[r*264 + c4*4]) = u;
    }
  }
  __syncthreads();                                             // B1

  // ---- GEMM2: a[p,l] = xs @ Mt^T  (each wave: 16 rows x 32 l, K=256) ----
  f32x4 acc2[2];
  acc2[0] = (f32x4){0.f, 0.f, 0.f, 0.f};
  acc2[1] = (f32x4){0.f, 0.f, 0.f, 0.f};
  #pragma unroll
  for (int kc = 0; kc < 8; ++kc) {
    half8 a = *(const half8*)(&xs[(rg*16 + l16)*264 + kc*32 + quad*8]);
    #pragma unroll
    for (int j = 0; j < 2; ++j) {
      half8 bf = *(const half8*)(mtf + ((size_t)(n*4 + lp*2 + j)*8 + kc)*512 + lane*8);
      acc2[j] = mfma16(a, bf, acc2[j]);
    }
  }

  // ---- softmax partials over this wave's 32 l-cols ----
  float mx_[4], ps_[4], e0_[4], e1_[4];
  #pragma unroll
  for (int r = 0; r < 4; ++r) {
    float s0 = acc2[0][r], s1 = acc2[1][r];
    float mx = fmaxf(s0, s1);
    #pragma unroll
    for (int off = 8; off >= 1; off >>= 1) mx = fmaxf(mx, __shfl_xor(mx, off, 64));
    float e0 = __expf(s0 - mx), e1 = __expf(s1 - mx);
    float ps = e0 + e1;
    #pragma unroll
    for (int off = 8; off >= 1; off >>= 1) ps += __shfl_xor(ps, off, 64);
    mx_[r] = mx; ps_[r] = ps; e0_[r] = e0; e1_[r] = e1;
    if (l16 == 0) {
      int row = rg*16 + quad*4 + r;
      parts[(row*2 + lp)*2]     = mx;
      parts[(row*2 + lp)*2 + 1] = ps;
    }
  }
  __syncthreads();                                             // B2

  // ---- combine partials (online-softmax merge), write aw ----
  #pragma unroll
  for (int r = 0; r < 4; ++r) {
    int row = rg*16 + quad*4 + r;
    float mxo = parts[(row*2 + (1 - lp))*2];
    float pso = parts[(row*2 + (1 - lp))*2 + 1];
    float g  = fmaxf(mx_[r], mxo);
    float sA = __expf(mx_[r] - g), sB = __expf(mxo - g);
    float inv = 1.0f / (ps_[r]*sA + pso*sB);
    float scl = sA * inv;
    aw[row*72 + (lp*2)*16 + l16]     = f2h(e0_[r]*scl);
    aw[row*72 + (lp*2 + 1)*16 + l16] = f2h(e1_[r]*scl);
  }

  // ---- GEMM4 (swapped: A=Wdf rows o, B=xs cols p) — no aw dependency,
  //      runs between aw-write and B3 to fill barrier skew ----
  f32x4 acc[4][4];           // [ot][ptt]: row=o=w*64+ot*16+quad*4+r, col=p=ptt*16+l16
  #pragma unroll
  for (int ot = 0; ot < 4; ++ot)
    #pragma unroll
    for (int ptt = 0; ptt < 4; ++ptt) acc[ot][ptt] = (f32x4){0.f, 0.f, 0.f, 0.f};
  #pragma unroll
  for (int kc = 0; kc < 8; ++kc) {
    half8 bx[4];             // xs B-frags, read ONCE per kc
    #pragma unroll
    for (int ptt = 0; ptt < 4; ++ptt)
      bx[ptt] = *(const half8*)(&xs[(ptt*16 + l16)*264 + kc*32 + quad*8]);
    #pragma unroll
    for (int ot = 0; ot < 4; ++ot) {
      half8 af = *(const half8*)(Wdf + ((size_t)(w*4 + ot)*8 + kc)*512 + lane*8);
      #pragma unroll
      for (int ptt = 0; ptt < 4; ++ptt) acc[ot][ptt] = mfma16(af, bx[ptt], acc[ot][ptt]);
    }
  }
  __syncthreads();                                             // B3

  // ---- GEMM3 (swapped: A=t3f rows o, B=aw cols p) ----
  #pragma unroll
  for (int kc3 = 0; kc3 < 2; ++kc3) {
    half8 ba[4];
    #pragma unroll
    for (int ptt = 0; ptt < 4; ++ptt)
      ba[ptt] = *(const half8*)(&aw[(ptt*16 + l16)*72 + kc3*32 + quad*8]);
    #pragma unroll
    for (int ot = 0; ot < 4; ++ot) {
      half8 af = *(const half8*)(t3f + ((size_t)(n*32 + w*4 + ot)*2 + kc3)*512 + lane*8);
      #pragma unroll
      for (int ptt = 0; ptt < 4; ++ptt) acc[ot][ptt] = mfma16(af, ba[ptt], acc[ot][ptt]);
    }
  }

  // ---- epilogue: per-ptt wave-private LDS transpose (f32x4 writes),
  //      full-line nontemporal float4 stores. Wave-local lgkmcnt only.
  //      sc element (p_row, o_col) at sc[p_row*68 + o_col], o_col in [0,64).
  float* sc = scb + w*1088;  // 16 x 68 f32 (4352 B per wave)
  #pragma unroll
  for (int ptt = 0; ptt < 4; ++ptt) {
    #pragma unroll
    for (int ot = 0; ot < 4; ++ot) {
      f32x4 v = acc[ot][ptt] + bias4[ot];
      *(f32x4*)&sc[l16*68 + ot*16 + quad*4] = v;   // row p_local=l16
    }
    #pragma unroll
    for (int shot = 0; shot < 4; ++shot) {
      int row = shot*4 + quad;                     // 4 rows/inst x 256B contiguous
      f32x4 v = *(f32x4*)&sc[row*68 + l16*4];
      __builtin_nontemporal_store(v,
        (f32x4*)(out + (size_t)(n*3136 + m0 + ptt*16 + row)*512 + w*64 + l16*4));
    }
  }
}

// ---------------------------------------------------------------------------
extern "C" void kernel_launch(void* const* d_in, const int* in_sizes, int n_in,
                              void* d_out, int out_size, void* d_ws, size_t ws_size,
                              hipStream_t stream) {
  const float* x  = (const float*)d_in[0];
  const float* t  = (const float*)d_in[1];
  const float* W1 = (const float*)d_in[2];
  const float* W2 = (const float*)d_in[3];
  const float* W3 = (const float*)d_in[4];
  const float* b3 = (const float*)d_in[5];
  const float* Wd = (const float*)d_in[6];
  const float* bd = (const float*)d_in[7];
  float* out = (float*)d_out;

  // workspace layout (bytes), 2,883,584 total — all fragment-linear f16
  char* ws = (char*)d_ws;
  u16* W1Tf = (u16*)(ws + 0);        //  131072
  u16* W2f  = (u16*)(ws + 131072);   //  131072
  u16* W3f  = (u16*)(ws + 262144);   //  262144
  u16* Wdf  = (u16*)(ws + 524288);   //  262144
  u16* tf   = (u16*)(ws + 786432);   //  524288
  u16* mtf  = (u16*)(ws + 1310720);  //  524288
  u16* t3f  = (u16*)(ws + 1835008);  //  1048576  (end 2883584)

  hipLaunchKernelGGL(prep_kernel, dim3(2560), dim3(256), 0, stream,
                     W1, W2, W3, Wd, t, W1Tf, W2f, W3f, Wdf, tf);
  hipLaunchKernelGGL(mt_t3_kernel, dim3(144), dim3(256), 0, stream,
                     tf, W1Tf, W2f, W3f, b3, mtf, t3f);
  hipLaunchKernelGGL(main_kernel, dim3(784), dim3(512), 0, stream,
                     x, Wdf, mtf, t3f, bd, out);
}